// Round 6
// baseline (1893.724 us; speedup 1.0000x reference)
//
#include <hip/hip_runtime.h>
#include <math.h>

#define S_LEN 16
#define BSZ   64
#define NN    10000
#define LAT   128
#define DH    257
#define KTAB  1024
#define CSTRIDE (KTAB + 8)    // costab leading dim
#define FSTRIDE (KTAB + 4)    // ftab leading dim
#define NTILE 64
#define NTILES 157            // ceil(10000/64)
#define BSPLIT 4              // attn batch split: 16 b per block
#define ATTN_BLKS (NTILES * BSPLIT)          // 628
#define GRU0 ATTN_BLKS                        // 628..755 gru
#define SCAT (ATTN_BLKS + 128)                // 756
#define COMB0 (SCAT + 1)                      // 757..820 combine
#define STEP_BLKS (COMB0 + 64)                // 821
#define SCALE 0.08838834764831845f
#define NEG1E9 -1000000000.0f

struct KP {
    const float *x, *t;
    const int *source, *target;
    const void *maskp;
    const float *tw, *tb_;
    const float *W_ih, *W_hh, *b_ih, *b_hh;
    const float *Wq, *bq, *Wk, *bk, *Wv, *bv, *W_out, *b_out;
    float *out;
    float *mem;
    float *newh[2], *uT[2], *u0qbk[2], *ftab[2], *partials[2];
    float *gtab, *costab;
    float *wv_out, *vconst, *W_ihT, *W_hhT, *BT, *uc, *kw0, *abk, *scal;
    int *modep;
};

// ============================================================================================
// GRU row r for step snext (+ fold in A(snext) for batch elems whose target last-writer is
// this row). Patch mem reads against step-sprev scatter set (scatter runs concurrently).
// sm: >= 2464 floats.
// ============================================================================================
__device__ void gru_a_block(const KP& p, float* sm, int r, int snext, int sprev, int zeroH) {
    int tid = threadIdx.x;
    int par = snext & 1;
    float* msg = sm;
    float* h   = sm + 132;
    float* gi3 = sm + 260;
    float* gh3 = sm + 644;
    float* hn  = sm + 1028;
    int*   itab = (int*)(sm + 1156);
    float* axv = sm + 1284;
    unsigned long long* amask = (unsigned long long*)(sm + 1288);
    float* udt = sm + 1296;
    float* red2 = sm + 1424;
    float* fpart = sm + 1440;

    int b = r & 63;
    int idx = (r < 64) ? p.source[snext * BSZ + b] : p.target[snext * BSZ + b];
    if (sprev >= 0 && tid < 128)
        itab[tid] = (tid < 64) ? p.source[sprev * BSZ + tid] : p.target[sprev * BSZ + (tid - 64)];
    const float* xs = p.x + (size_t)(snext * BSZ + b) * NN;
    const float* ts = p.t + (size_t)(snext * BSZ + b) * NN;
    if (tid == 0) msg[0] = xs[idx];
    if (tid < 128) {
        float tv = ts[idx];
        msg[1 + tid] = __cosf(tv * p.tw[tid] + p.tb_[tid]);
    }
    __syncthreads();
    int w = -1;
    if (sprev >= 0) {
        for (int k = 127; k >= 0; --k) if (itab[k] == idx) { w = k; break; }
    }
    if (tid < 128) {
        h[tid] = zeroH ? 0.f
               : (w >= 0 ? p.newh[par ^ 1][w * LAT + tid] : p.mem[(size_t)idx * LAT + tid]);
    }
    __syncthreads();
    if (tid < 128) {
        int j = tid;
        float a0 = p.b_ih[j], a1 = p.b_ih[128 + j], a2 = p.b_ih[256 + j];
#pragma unroll 4
        for (int d = 0; d < 129; ++d) {
            float m = msg[d];
            const float* col = p.W_ihT + d * 384;
            a0 += m * col[j]; a1 += m * col[128 + j]; a2 += m * col[256 + j];
        }
        gi3[j] = a0; gi3[128 + j] = a1; gi3[256 + j] = a2;
    } else {
        int j = tid - 128;
        float a0 = p.b_hh[j], a1 = p.b_hh[128 + j], a2 = p.b_hh[256 + j];
#pragma unroll 4
        for (int l = 0; l < 128; ++l) {
            float hv = h[l];
            const float* col = p.W_hhT + l * 384;
            a0 += hv * col[j]; a1 += hv * col[128 + j]; a2 += hv * col[256 + j];
        }
        gh3[j] = a0; gh3[128 + j] = a1; gh3[256 + j] = a2;
    }
    __syncthreads();
    if (tid < 128) {
        int j = tid;
        float rr = 1.f / (1.f + __expf(-(gi3[j] + gh3[j])));
        float zz = 1.f / (1.f + __expf(-(gi3[128 + j] + gh3[128 + j])));
        float nn2 = tanhf(gi3[256 + j] + rr * gh3[256 + j]);
        float val = (1.f - zz) * nn2 + zz * h[j];
        hn[j] = val;
        p.newh[par][r * LAT + j] = val;
    }
    if (r < 64) return;

    // ---------------- A(snext) for {b2 : s_last(b2) == r-64} ----------------
    int rT = r - 64;
    int* tg = itab;   // reuse
    __syncthreads();
    if (tid < 64) tg[tid] = p.target[snext * BSZ + tid];
    __syncthreads();
    unsigned long long mask = 0;
    if (tid < 64) {
        int myt = tg[tid]; int sl = 0;
        for (int k = 0; k < 64; ++k) if (tg[k] == myt) sl = k;
        mask = __ballot(sl == rT);
    }
    if (tid == 0) *amask = mask;
    __syncthreads();
    unsigned long long bl = *amask;
    float* u0qb = p.u0qbk[par];
    float* uTb  = p.uT[par];
    float* ftb  = p.ftab[par];
    while (bl) {
        int b2 = __ffsll((long long)bl) - 1; bl &= bl - 1;
        if (tid == 0) *axv = p.x[(size_t)(snext * BSZ + b2) * NN + tg[b2]];
        __syncthreads();
        float xv = *axv;
        {   // u[d] = uc[d] + xv*kw0[d] + hn . BT[:,d]
            int d = tid;
            float a0 = 0.f, a1 = 0.f;
#pragma unroll 4
            for (int l = 0; l < 128; l += 2) {
                a0 += hn[l] * p.BT[l * 260 + d];
                a1 += hn[l + 1] * p.BT[(l + 1) * 260 + d];
            }
            float a = p.uc[d] + xv * p.kw0[d] + a0 + a1;
            if (d == 0) u0qb[b2] = a;
            else if (d <= 128) uTb[(d - 1) * BSZ + b2] = a;
            else udt[d - 129] = a;
            if (tid == 0) {
                float c0 = 0.f, c1 = 0.f;
#pragma unroll 4
                for (int l = 0; l < 128; l += 2) {
                    c0 += hn[l] * p.BT[l * 260 + 256];
                    c1 += hn[l + 1] * p.BT[(l + 1) * 260 + 256];
                }
                udt[127] = p.uc[256] + xv * p.kw0[256] + c0 + c1;
            }
        }
        if (tid >= 192) {   // qbk
            int i = tid - 192;
            float a = hn[i] * p.abk[i] + hn[64 + i] * p.abk[64 + i];
            for (int off = 32; off; off >>= 1) a += __shfl_down(a, off, 64);
            if (i == 0) u0qb[64 + b2] = p.scal[0] + xv * p.scal[1] + a;
        }
        __syncthreads();
        {   // ftab: 8 points/thread, L split 2 ways
            int pi = tid & 127, lc = tid >> 7;
            int l0 = lc * 64;
            float a0x = 0.f, a0y = 0.f, a0z = 0.f, a0w = 0.f;
            float a1x = 0.f, a1y = 0.f, a1z = 0.f, a1w = 0.f;
#pragma unroll 4
            for (int l = l0; l < l0 + 64; ++l) {
                float ul = udt[l];
                const float* cp = &p.costab[l * CSTRIDE + pi * 8];
                float4 c0 = *(const float4*)cp;
                float4 c1 = *(const float4*)(cp + 4);
                a0x += ul * c0.x; a0y += ul * c0.y; a0z += ul * c0.z; a0w += ul * c0.w;
                a1x += ul * c1.x; a1y += ul * c1.y; a1z += ul * c1.z; a1w += ul * c1.w;
            }
            if (lc) {
                float* fp = &fpart[pi * 8];
                *(float4*)fp = make_float4(a0x, a0y, a0z, a0w);
                *(float4*)(fp + 4) = make_float4(a1x, a1y, a1z, a1w);
            }
            if (pi == 127) {
                float a = 0.f;
                for (int l = l0; l < l0 + 64; ++l) a += udt[l] * p.costab[l * CSTRIDE + KTAB];
                red2[lc] = a;
            }
            __syncthreads();
            if (lc == 0) {
                const float* fp = &fpart[pi * 8];
                a0x += fp[0]; a0y += fp[1]; a0z += fp[2]; a0w += fp[3];
                a1x += fp[4]; a1y += fp[5]; a1z += fp[6]; a1w += fp[7];
                float* fo = &ftb[b2 * FSTRIDE + pi * 8];
                *(float4*)fo = make_float4(a0x, a0y, a0z, a0w);
                *(float4*)(fo + 4) = make_float4(a1x, a1y, a1z, a1w);
            }
            if (tid == 0) ftb[b2 * FSTRIDE + KTAB] = red2[0] + red2[1];
        }
        __syncthreads();
    }
}

// ============================================================================================
__device__ void combine256(const float* __restrict__ partials, const float* __restrict__ vconst,
                           float* __restrict__ out, float* sm, int b, int ps) {
    int tid = threadIdx.x;
    float m = -3.0e38f, d = 0.f, n = 0.f;
    if (tid < NTILES) {
        float4 v = *((const float4*)partials + b * NTILES + tid);
        m = v.x; d = v.y; n = v.z;
    }
#pragma unroll
    for (int off = 32; off; off >>= 1) {
        float mo = __shfl_down(m, off, 64);
        float d2 = __shfl_down(d, off, 64);
        float n2 = __shfl_down(n, off, 64);
        float M = fmaxf(m, mo);
        float e1 = __expf(m - M), e2 = __expf(mo - M);
        d = d * e1 + d2 * e2; n = n * e1 + n2 * e2; m = M;
    }
    float* red = sm;
    int w = tid >> 6;
    if ((tid & 63) == 0) { red[w * 3] = m; red[w * 3 + 1] = d; red[w * 3 + 2] = n; }
    __syncthreads();
    if (tid == 0) {
        float M = red[0], D = red[1], Nm = red[2];
        for (int k2 = 1; k2 < 4; ++k2) {
            float m2 = red[k2 * 3], d2 = red[k2 * 3 + 1], n2 = red[k2 * 3 + 2];
            float M2 = fmaxf(M, m2);
            float e1 = __expf(M - M2), e2 = __expf(m2 - M2);
            D = D * e1 + d2 * e2; Nm = Nm * e1 + n2 * e2; M = M2;
        }
        out[ps * BSZ + b] = Nm / D + vconst[0];
    }
}

// ============================================================================================
__global__ __launch_bounds__(256) void setup_kernel(KP p) {
    int blk = blockIdx.x, tid = threadIdx.x;
    __shared__ float sm[256];
    if (blk < 256) {
        int gtid = blk * 256 + tid;
        const int GS = 256 * 256;
        for (int i = gtid; i < 129 * 384; i += GS) { int d = i / 384, j = i % 384; p.W_ihT[i] = p.W_ih[j * 129 + d]; }
        for (int i = gtid; i < 128 * 384; i += GS) { int l = i / 384, j = i % 384; p.W_hhT[i] = p.W_hh[j * 128 + l]; }
        for (int pp = gtid; pp <= KTAB; pp += GS) {
            float tv = (float)pp * (1.0f / KTAB);
            for (int l = 0; l < 128; ++l) p.costab[l * CSTRIDE + pp] = __cosf(tv * p.tw[l] + p.tb_[l]);
        }
    } else if (blk == 256) {
        for (int d = tid; d < DH; d += 256) {
            float a = 0.f;
            for (int j = 0; j < LAT; ++j) a += p.Wv[d * LAT + j] * p.W_out[j];
            p.wv_out[d] = a;
        }
        if (tid == 0) {
            float a = p.b_out[0];
            for (int j = 0; j < LAT; ++j) a += p.bv[j] * p.W_out[j];
            p.vconst[0] = a;
        }
        __shared__ int hasHigh, hasFloat;
        if (tid == 0) { hasHigh = 0; hasFloat = 0; }
        __syncthreads();
        const int* mask = (const int*)p.maskp;
        for (int i = tid; i < 4096; i += 256) {
            int v = mask[i];
            if ((unsigned)v > 1u) atomicOr(&hasHigh, 1);
            if (v == 0x3F800000) atomicOr(&hasFloat, 1);
        }
        __syncthreads();
        if (tid == 0) p.modep[0] = hasFloat ? 2 : (hasHigh ? 1 : 0);
    } else if (blk < 385) {          // BT row l
        int l = blk - 257;
        float* vrow = sm;
        if (tid < 128) vrow[tid] = p.Wq[(1 + l) * LAT + tid];
        __syncthreads();
        for (int d = tid; d < DH; d += 256) {
            const float* wkr = p.Wk + d * LAT;
            float a = 0.f;
#pragma unroll 4
            for (int j = 0; j < 128; ++j) a += wkr[j] * vrow[j];
            p.BT[l * 260 + d] = a;
        }
    } else if (blk == 385) {         // kw0 = Wk @ Wq[0,:]
        float* vrow = sm;
        if (tid < 128) vrow[tid] = p.Wq[tid];
        __syncthreads();
        for (int d = tid; d < DH; d += 256) {
            const float* wkr = p.Wk + d * LAT;
            float a = 0.f;
#pragma unroll 4
            for (int j = 0; j < 128; ++j) a += wkr[j] * vrow[j];
            p.kw0[d] = a;
        }
    } else if (blk == 386) {         // uc = Wk @ qconst
        __shared__ float cosv[128], qc[128];
        if (tid < 128) cosv[tid] = __cosf(p.tb_[tid]);
        __syncthreads();
        if (tid < 128) {
            float a = p.bq[tid];
            for (int j = 0; j < 128; ++j) a += cosv[j] * p.Wq[(129 + j) * LAT + tid];
            qc[tid] = a;
        }
        __syncthreads();
        for (int d = tid; d < DH; d += 256) {
            const float* wkr = p.Wk + d * LAT;
            float a = 0.f;
#pragma unroll 4
            for (int j = 0; j < 128; ++j) a += wkr[j] * qc[j];
            p.uc[d] = a;
        }
    } else {                         // abk + scal
        __shared__ float bkv[128], cosv[128], tpart[128];
        if (tid < 128) { bkv[tid] = p.bk[tid]; cosv[tid] = __cosf(p.tb_[tid]); }
        __syncthreads();
        if (tid < 128) {
            const float* wqr = p.Wq + (1 + tid) * LAT;
            float a = 0.f;
#pragma unroll 4
            for (int j = 0; j < 128; ++j) a += wqr[j] * bkv[j];
            p.abk[tid] = a;
        } else {
            int j = tid - 128;
            const float* wqr = p.Wq + (129 + j) * LAT;
            float a = 0.f;
#pragma unroll 4
            for (int l = 0; l < 128; ++l) a += wqr[l] * bkv[l];
            tpart[j] = cosv[j] * a;
        }
        __syncthreads();
        if (tid == 0) {
            float s0 = 0.f, s1 = 0.f;
            for (int l = 0; l < 128; ++l) { s0 += p.bq[l] * bkv[l]; s1 += p.Wq[l] * bkv[l]; }
            for (int j = 0; j < 128; ++j) s0 += tpart[j];
            p.scal[0] = s0; p.scal[1] = s1;
        }
    }
}

// ============================================================================================
__global__ __launch_bounds__(256) void pre2_kernel(KP p) {
    __shared__ __align__(16) float sm[2464];
    int blk = blockIdx.x, tid = threadIdx.x;
    if (blk < 5) {
        __shared__ float wv_s[LAT];
        if (tid < LAT) wv_s[tid] = p.wv_out[129 + tid];
        __syncthreads();
        int pp = blk * 256 + tid;
        if (pp <= KTAB) {
            float a = 0.f;
            for (int l = 0; l < 128; ++l) a += wv_s[l] * p.costab[l * CSTRIDE + pp];
            p.gtab[pp] = a;
        }
        return;
    }
    gru_a_block(p, sm, blk - 5, /*snext=*/0, /*sprev=*/-1, /*zeroH=*/1);
}

// ============================================================================================
// step kernel: 0..627 attn (157 tiles x 4 b-quarters); 628..755 gru(s+1)+A(s+1);
// 756 scatter(s); 757..820 combine(s-1). No intra-kernel cross-block deps.
// ============================================================================================
__global__ __launch_bounds__(256) void step_kernel(KP p, int s) {
    __shared__ __align__(16) float sm[7680];
    int blk = blockIdx.x, tid = threadIdx.x;
    int par = s & 1;

    if (blk >= GRU0 && blk < SCAT) {
        if (s < S_LEN - 1)
            gru_a_block(p, sm, blk - GRU0, s + 1, s, 0);
        return;
    }
    if (blk == SCAT) {   // scatter(s): newh[par] -> mem (readers patch; no race)
        int* idxs  = (int*)sm;
        int* alive = idxs + 128;
        if (tid < 128) idxs[tid] = (tid < 64) ? p.source[s * BSZ + tid] : p.target[s * BSZ + (tid - 64)];
        __syncthreads();
        if (tid < 128) {
            int i2 = idxs[tid];
            int a = 1;
            for (int r2 = tid + 1; r2 < 128; ++r2)
                if (idxs[r2] == i2) { a = 0; break; }
            alive[tid] = a;
        }
        __syncthreads();
        int row = tid >> 1, q2 = tid & 1;
        if (alive[row]) {
            const float4* srcp = (const float4*)(p.newh[par] + row * LAT + q2 * 64);
            float4* dstp = (float4*)(p.mem + (size_t)idxs[row] * LAT + q2 * 64);
#pragma unroll
            for (int j = 0; j < 16; ++j) dstp[j] = srcp[j];
        }
        return;
    }
    if (blk >= COMB0) {   // combine(s-1)
        if (s > 0) combine256(p.partials[par ^ 1], p.vconst, p.out, sm, blk - COMB0, s - 1);
        return;
    }

    // ---------------- attn tile, 16 batch elems per block ----------------
    float* memT   = sm;                  // 64*72 = 4608
    float* uTs    = sm + 4608;           // 128*20 = 2560
    float* wv_s   = sm + 7168;           // 128
    float* memv_s = sm + 7296;           // 64
    float* u0_s   = sm + 7360;           // 16
    float* qbk_s  = sm + 7376;           // 16
    int*   idxs   = (int*)(sm + 7392);   // 128
    int*   prow   = (int*)(sm + 7520);   // 64

    int tile = blk >> 2, bq = blk & 3;
    int n0 = tile * NTILE, b0 = bq * 16;
    int tb = tid >> 4, tn = tid & 15;
    int b = b0 + tb;
    int nvalid = NN - n0; if (nvalid > NTILE) nvalid = NTILE;

    // ---- EARLY PREFETCH: x/t/mask + ftab/gtab interp endpoints (all step-s-ready) ----
    int mode = p.modep[0];
    const int* m32 = (const int*)p.maskp;
    const unsigned char* m8 = (const unsigned char*)p.maskp;
    const float* mf = (const float*)p.maskp;
    size_t base = (size_t)(s * BSZ + b) * NN + n0 + tn * 4;
    float xv4[4], tv4[4]; int msk[4], vld[4];
    if (tn * 4 + 3 < nvalid) {
        float4 xx = *(const float4*)(p.x + base);
        float4 tt = *(const float4*)(p.t + base);
        xv4[0] = xx.x; xv4[1] = xx.y; xv4[2] = xx.z; xv4[3] = xx.w;
        tv4[0] = tt.x; tv4[1] = tt.y; tv4[2] = tt.z; tv4[3] = tt.w;
        if (mode == 1) {
            unsigned mw = *(const unsigned*)(m8 + base);
            msk[0] = mw & 0xff; msk[1] = (mw >> 8) & 0xff; msk[2] = (mw >> 16) & 0xff; msk[3] = (mw >> 24) & 0xff;
        } else if (mode == 2) {
            float4 mm = *(const float4*)(mf + base);
            msk[0] = (mm.x != 0.f); msk[1] = (mm.y != 0.f); msk[2] = (mm.z != 0.f); msk[3] = (mm.w != 0.f);
        } else {
            int4 mm = *(const int4*)(m32 + base);
            msk[0] = mm.x; msk[1] = mm.y; msk[2] = mm.z; msk[3] = mm.w;
        }
        vld[0] = vld[1] = vld[2] = vld[3] = 1;
    } else {
        for (int j = 0; j < 4; ++j) {
            int n = tn * 4 + j;
            vld[j] = (n < nvalid);
            if (vld[j]) {
                xv4[j] = p.x[base + j]; tv4[j] = p.t[base + j];
                msk[j] = (mode == 1) ? (int)m8[base + j] : (mode == 2) ? (mf[base + j] != 0.f) : m32[base + j];
            } else { xv4[j] = 0.f; tv4[j] = 0.f; msk[j] = 0; }
        }
    }
    // gather endpoints (t-dependent only; issued before QK^T so latency hides)
    const float* ft = p.ftab[par] + b * FSTRIDE;
    const float* gtab = p.gtab;
    float fr[4], f0v[4], f1v[4], g0v[4], g1v[4];
#pragma unroll
    for (int j = 0; j < 4; ++j) {
        float pq = tv4[j] * (float)KTAB;
        pq = fminf(fmaxf(pq, 0.f), (float)KTAB - 0.001f);
        int ii = (int)pq;
        fr[j] = pq - (float)ii;
        f0v[j] = ft[ii]; f1v[j] = ft[ii + 1];
        g0v[j] = gtab[ii]; g1v[j] = gtab[ii + 1];
    }

    // ---- stage uTs (both halves, 16 cols) ----
    {
        int l = tid >> 1, bb = (tid & 1) * 8;
        const float* uTb = p.uT[par];
        float4 v0 = *(const float4*)&uTb[l * BSZ + b0 + bb];
        float4 v1 = *(const float4*)&uTb[l * BSZ + b0 + bb + 4];
        *(float4*)&uTs[l * 20 + bb] = v0;
        *(float4*)&uTs[l * 20 + bb + 4] = v1;
    }
    if (tid < 128) wv_s[tid] = p.wv_out[1 + tid];
    if (tid < 16) { u0_s[tid] = p.u0qbk[par][b0 + tid]; qbk_s[tid] = p.u0qbk[par][64 + b0 + tid]; }
    if (tid < 64) memv_s[tid] = 0.f;
    if (tid < 128) idxs[tid] = (tid < 64) ? p.source[s * BSZ + tid] : p.target[s * BSZ + (tid - 64)];
    __syncthreads();
    if (tid < 64) {
        int node = n0 + tid; int w = -1;
        for (int k = 127; k >= 0; --k) if (idxs[k] == node) { w = k; break; }
        prow[tid] = w;
    }

    float acc0 = 0.f, acc1 = 0.f, acc2 = 0.f, acc3 = 0.f;
    const float* nh = p.newh[par];
    for (int l0 = 0; l0 < 128; l0 += 64) {
        __syncthreads();
        {   // stage mem (or patched newh row) -> memT transposed
            int n_l = tid & 63, lq = (tid >> 6) * 16;
            if (n_l < nvalid) {
                int w = prow[n_l];
                const float* mrow = (w >= 0) ? (nh + w * LAT + l0 + lq)
                                             : (p.mem + (size_t)(n0 + n_l) * LAT + l0 + lq);
                float4 a0 = *(const float4*)(mrow + 0);
                float4 a1 = *(const float4*)(mrow + 4);
                float4 a2 = *(const float4*)(mrow + 8);
                float4 a3 = *(const float4*)(mrow + 12);
                memT[(lq + 0) * 72 + n_l] = a0.x; memT[(lq + 1) * 72 + n_l] = a0.y;
                memT[(lq + 2) * 72 + n_l] = a0.z; memT[(lq + 3) * 72 + n_l] = a0.w;
                memT[(lq + 4) * 72 + n_l] = a1.x; memT[(lq + 5) * 72 + n_l] = a1.y;
                memT[(lq + 6) * 72 + n_l] = a1.z; memT[(lq + 7) * 72 + n_l] = a1.w;
                memT[(lq + 8) * 72 + n_l] = a2.x; memT[(lq + 9) * 72 + n_l] = a2.y;
                memT[(lq + 10) * 72 + n_l] = a2.z; memT[(lq + 11) * 72 + n_l] = a2.w;
                memT[(lq + 12) * 72 + n_l] = a3.x; memT[(lq + 13) * 72 + n_l] = a3.y;
                memT[(lq + 14) * 72 + n_l] = a3.z; memT[(lq + 15) * 72 + n_l] = a3.w;
            } else {
                for (int j = 0; j < 16; ++j) memT[(lq + j) * 72 + n_l] = 0.f;
            }
        }
        __syncthreads();
        if (tid < 64) {   // memv partial
            float a = memv_s[tid];
            for (int l = 0; l < 64; ++l) a += wv_s[l0 + l] * memT[l * 72 + tid];
            memv_s[tid] = a;
        }
        for (int l = 0; l < 64; ++l) {
            float u = uTs[(l0 + l) * 20 + tb];
            float4 mv = *(const float4*)&memT[l * 72 + tn * 4];
            acc0 += u * mv.x; acc1 += u * mv.y; acc2 += u * mv.z; acc3 += u * mv.w;
        }
    }
    __syncthreads();

    const float c0 = p.wv_out[0];
    float accs[4] = {acc0, acc1, acc2, acc3};
    float pm = -3.0e38f, pd = 0.f, pn = 0.f;
#pragma unroll
    for (int j = 0; j < 4; ++j) {
        if (!vld[j]) continue;
        float fv = f0v[j] + (f1v[j] - f0v[j]) * fr[j];
        float gv = g0v[j] + (g1v[j] - g0v[j]) * fr[j];
        float sc = SCALE * (xv4[j] * u0_s[tb] + accs[j] + fv + qbk_s[tb]);
        if (msk[j] == 0) sc = NEG1E9;
        float val = xv4[j] * c0 + memv_s[tn * 4 + j] + gv;
        if (sc > pm) {
            float a = __expf(pm - sc);
            pd = pd * a + 1.f;
            pn = pn * a + val;
            pm = sc;
        } else {
            float e = __expf(sc - pm);
            pd += e;
            pn += e * val;
        }
    }
#pragma unroll
    for (int mk2 = 1; mk2 < 16; mk2 <<= 1) {
        float mo = __shfl_xor(pm, mk2);
        float d2 = __shfl_xor(pd, mk2);
        float n2 = __shfl_xor(pn, mk2);
        float M = fmaxf(pm, mo);
        float e1 = __expf(pm - M), e2 = __expf(mo - M);
        pd = pd * e1 + d2 * e2;
        pn = pn * e1 + n2 * e2;
        pm = M;
    }
    if (tn == 0)
        *(float4*)&p.partials[par][(size_t)(b * NTILES + tile) * 4] = make_float4(pm, pd, pn, 0.f);
}

// ============================================================================================
__global__ __launch_bounds__(256) void tail2_kernel(KP p) {
    __shared__ float sm[16];
    combine256(p.partials[(S_LEN - 1) & 1], p.vconst, p.out, sm, blockIdx.x, S_LEN - 1);
}

extern "C" void kernel_launch(void* const* d_in, const int* in_sizes, int n_in,
                              void* d_out, int out_size, void* d_ws, size_t ws_size,
                              hipStream_t stream) {
    KP kp;
    kp.x      = (const float*)d_in[0];
    kp.t      = (const float*)d_in[1];
    kp.source = (const int*)d_in[2];
    kp.target = (const int*)d_in[3];
    kp.maskp  = (const void*)d_in[4];
    kp.tw     = (const float*)d_in[5];
    kp.tb_    = (const float*)d_in[6];
    kp.W_ih   = (const float*)d_in[7];
    kp.W_hh   = (const float*)d_in[8];
    kp.b_ih   = (const float*)d_in[9];
    kp.b_hh   = (const float*)d_in[10];
    kp.Wq     = (const float*)d_in[11];
    kp.bq     = (const float*)d_in[12];
    kp.Wk     = (const float*)d_in[13];
    kp.bk     = (const float*)d_in[14];
    kp.Wv     = (const float*)d_in[15];
    kp.bv     = (const float*)d_in[16];
    kp.W_out  = (const float*)d_in[17];
    kp.b_out  = (const float*)d_in[18];
    kp.out    = (float*)d_out;

    float* w = (float*)d_ws;
    kp.mem        = w; w += (size_t)NN * LAT;       // 1,280,000
    kp.newh[0]    = w; w += 128 * LAT;
    kp.newh[1]    = w; w += 128 * LAT;
    kp.uT[0]      = w; w += LAT * BSZ;
    kp.uT[1]      = w; w += LAT * BSZ;
    kp.u0qbk[0]   = w; w += 128;
    kp.u0qbk[1]   = w; w += 128;
    kp.ftab[0]    = w; w += BSZ * FSTRIDE;
    kp.ftab[1]    = w; w += BSZ * FSTRIDE;
    kp.partials[0] = w; w += (size_t)BSZ * NTILES * 4;
    kp.partials[1] = w; w += (size_t)BSZ * NTILES * 4;
    kp.gtab       = w; w += 1056;
    kp.costab     = w; w += LAT * CSTRIDE;          // 132,096
    kp.wv_out     = w; w += 288;
    kp.vconst     = w; w += 32;
    kp.W_ihT      = w; w += 129 * 384;
    kp.W_hhT      = w; w += 128 * 384;
    kp.BT         = w; w += 128 * 260;
    kp.uc         = w; w += 288;
    kp.kw0        = w; w += 288;
    kp.abk        = w; w += 128;
    kp.scal       = w; w += 32;
    kp.modep      = (int*)w; w += 32;

    hipMemsetAsync(kp.mem, 0, (size_t)NN * LAT * sizeof(float), stream);
    setup_kernel<<<388, 256, 0, stream>>>(kp);
    pre2_kernel<<<133, 256, 0, stream>>>(kp);
    for (int s = 0; s < S_LEN; ++s)
        step_kernel<<<STEP_BLKS, 256, 0, stream>>>(kp, s);
    tail2_kernel<<<64, 256, 0, stream>>>(kp);
}